// Round 1
// baseline (336.923 us; speedup 1.0000x reference)
//
#include <hip/hip_runtime.h>
#include <math.h>

// Problem dims
#define HD    2048
#define QKVD  8192
#define TVD   4096
#define NVHD  32
#define NKHD  16
#define KDD   128
#define VDD   128
#define PROJN (QKVD + TVD + 2*NVHD)   // 12352

// ---------- helpers ----------
__device__ __forceinline__ float sigmoidf_(float x) { return 1.0f / (1.0f + expf(-x)); }
__device__ __forceinline__ float siluf_(float x)    { return x / (1.0f + expf(-x)); }
__device__ __forceinline__ float softplusf_(float x){ return (x > 20.0f) ? x : log1pf(expf(x)); }

__device__ __forceinline__ float waveReduceSum(float v) {
#pragma unroll
    for (int o = 32; o > 0; o >>= 1) v += __shfl_down(v, o, 64);
    return v;
}

// 256-thread block reduce; `red` must have >=4 floats of LDS. All threads get result.
__device__ __forceinline__ float blockReduceSum256(float v, float* red) {
    const int lane = threadIdx.x & 63, wid = threadIdx.x >> 6;
    v = waveReduceSum(v);
    if (lane == 0) red[wid] = v;
    __syncthreads();
    float s = red[0] + red[1] + red[2] + red[3];
    __syncthreads();   // safe reuse of red
    return s;
}

// ---------- K0: rms1 -> h ; zero rms2 accumulator ----------
__global__ void k0_rms1(const float* __restrict__ x, const float* __restrict__ w1,
                        float* __restrict__ hvec, float* __restrict__ ss2) {
    __shared__ float red[4];
    const int t = threadIdx.x;
    float s = 0.f;
#pragma unroll
    for (int i = t; i < HD/4; i += 256) {
        float4 v = ((const float4*)x)[i];
        s += v.x*v.x + v.y*v.y + v.z*v.z + v.w*v.w;
    }
    s = blockReduceSum256(s, red);
    const float r = rsqrtf(s / (float)HD + 1e-6f);
#pragma unroll
    for (int i = t; i < HD/4; i += 256) {
        float4 v = ((const float4*)x)[i];
        float4 w = ((const float4*)w1)[i];
        float4 o = make_float4(v.x*r*(1.f+w.x), v.y*r*(1.f+w.y),
                               v.z*r*(1.f+w.z), v.w*r*(1.f+w.w));
        ((float4*)hvec)[i] = o;
    }
    if (t == 0) *ss2 = 0.f;
}

// ---------- generic wave-per-row GEMV: out[row] = dot(W[row,:], v) ----------
template<int COLS>
__global__ void gemv_rows(const float* __restrict__ W, const float* __restrict__ v,
                          float* __restrict__ out) {
    const int wid = threadIdx.x >> 6, lane = threadIdx.x & 63;
    const int row = blockIdx.x * 4 + wid;
    const float4* Wr = (const float4*)(W + (size_t)row * COLS);
    const float4* vr = (const float4*)v;
    float acc = 0.f;
#pragma unroll
    for (int i = 0; i < COLS/256; i++) {
        float4 a = Wr[lane + i*64];
        float4 b = vr[lane + i*64];
        acc += a.x*b.x + a.y*b.y + a.z*b.z + a.w*b.w;
    }
    acc = waveReduceSum(acc);
    if (lane == 0) out[row] = acc;
}

// ---------- K2: conv update + L2 norms + gated delta-rule state update + y-gate ----------
__global__ void k2_ssm(const float* __restrict__ proj,
                       const float* __restrict__ conv_state,
                       const float* __restrict__ conv_weight,
                       const float* __restrict__ ssm_state,
                       const float* __restrict__ A_log,
                       const float* __restrict__ dt_bias,
                       const float* __restrict__ norm_weight,
                       float* __restrict__ new_conv_state,
                       float* __restrict__ new_ssm,
                       float* __restrict__ yout) {
    const int head  = blockIdx.x;     // 0..31
    const int t     = threadIdx.x;    // 0..255
    const int qhead = head >> 1;      // ratio = 2

    __shared__ float red[4];
    __shared__ float q_s[KDD], k_s[KDD], v_s[VDD];
    __shared__ float skr2[256], sqr2[256];

    float qv = 0.f, kv = 0.f, vv = 0.f;
    if (t < 128) {
        // q channel
        int cq = qhead*KDD + t;
        float4 cs = *(const float4*)(conv_state + (size_t)cq*4);
        float4 w  = *(const float4*)(conv_weight + (size_t)cq*4);
        float xm  = proj[cq];
        qv = siluf_(cs.y*w.x + cs.z*w.y + cs.w*w.z + xm*w.w);
        *(float4*)(new_conv_state + (size_t)cq*4) = make_float4(cs.y, cs.z, cs.w, xm);
        // k channel
        int ck = 2048 + qhead*KDD + t;
        cs = *(const float4*)(conv_state + (size_t)ck*4);
        w  = *(const float4*)(conv_weight + (size_t)ck*4);
        xm = proj[ck];
        kv = siluf_(cs.y*w.x + cs.z*w.y + cs.w*w.z + xm*w.w);
        *(float4*)(new_conv_state + (size_t)ck*4) = make_float4(cs.y, cs.z, cs.w, xm);
        // v channel
        int cv = 4096 + head*VDD + t;
        cs = *(const float4*)(conv_state + (size_t)cv*4);
        w  = *(const float4*)(conv_weight + (size_t)cv*4);
        xm = proj[cv];
        vv = siluf_(cs.y*w.x + cs.z*w.y + cs.w*w.z + xm*w.w);
        *(float4*)(new_conv_state + (size_t)cv*4) = make_float4(cs.y, cs.z, cs.w, xm);
    }

    const float sq = blockReduceSum256(qv*qv, red);
    const float sk = blockReduceSum256(kv*kv, red);
    const float qn = qv / fmaxf(sqrtf(sq), 1e-12f) * 0.08838834764831845f; // * 128^-0.5
    const float kn = kv / fmaxf(sqrtf(sk), 1e-12f);
    const float kq = blockReduceSum256(qn*kn, red);

    if (t < 128) { q_s[t] = qn; k_s[t] = kn; v_s[t] = vv; }
    __syncthreads();

    // scalars (uniform)
    const float a_raw = proj[QKVD + TVD + head];
    const float b_raw = proj[QKVD + TVD + NVHD + head];
    const float beta  = sigmoidf_(b_raw);
    const float g     = -expf(A_log[head]) * softplusf_(a_raw + dt_bias[head]);
    const float decay = expf(g);

    // state pass 1: per-column partial dots over half the k-range
    const int col = t & 127;
    const int kh  = t >> 7;                // 0 or 1
    const float* Sp = ssm_state + (size_t)head*KDD*VDD + (size_t)kh*64*VDD + col;
    float skr = 0.f, sqr = 0.f;
#pragma unroll 16
    for (int k = 0; k < 64; k++) {
        float s = Sp[k*VDD];
        skr += s * k_s[kh*64 + k];
        sqr += s * q_s[kh*64 + k];
    }
    skr2[t] = skr; sqr2[t] = sqr;
    __syncthreads();
    const float Skr = skr2[col] + skr2[col + 128];
    const float Sqr = sqr2[col] + sqr2[col + 128];
    const float delta = (v_s[col] - decay * Skr) * beta;

    // state pass 2: write new_ssm (re-read is L2-hot)
    float* Np = new_ssm + (size_t)head*KDD*VDD + (size_t)kh*64*VDD + col;
#pragma unroll 16
    for (int k = 0; k < 64; k++) {
        float s = Sp[k*VDD];
        Np[k*VDD] = decay * s + k_s[kh*64 + k] * delta;
    }

    // y = decay*<S[:,v],q> + delta*<k,q>  (owned by kh==0 threads)
    const float y = decay * Sqr + delta * kq;
    const float sy = blockReduceSum256((kh == 0) ? y*y : 0.f, red);
    if (t < 128) {
        const float r  = rsqrtf(sy / (float)VDD + 1e-6f);
        const float z  = proj[QKVD + head*VDD + t];
        yout[head*VDD + t] = y * r * norm_weight[t] * siluf_(z);
    }
}

// ---------- K3: attn_out GEMV + residual + rms2 partial sumsq ----------
__global__ void k3_outproj(const float* __restrict__ W, const float* __restrict__ yout,
                           const float* __restrict__ x, float* __restrict__ x1,
                           float* __restrict__ ss2) {
    __shared__ float part[4];
    const int wid = threadIdx.x >> 6, lane = threadIdx.x & 63;
    const int row = blockIdx.x * 4 + wid;
    const float4* Wr = (const float4*)(W + (size_t)row * TVD);
    const float4* vr = (const float4*)yout;
    float acc = 0.f;
#pragma unroll
    for (int i = 0; i < TVD/256; i++) {
        float4 a = Wr[lane + i*64];
        float4 b = vr[lane + i*64];
        acc += a.x*b.x + a.y*b.y + a.z*b.z + a.w*b.w;
    }
    acc = waveReduceSum(acc);
    if (lane == 0) {
        float xv = x[row] + acc;
        x1[row] = xv;
        part[wid] = xv * xv;
    }
    __syncthreads();
    if (threadIdx.x == 0) atomicAdd(ss2, part[0] + part[1] + part[2] + part[3]);
}

// ---------- K4: gate & up dual GEMV with rms2 folded in ----------
__global__ void k4_gateup(const float* __restrict__ GW, const float* __restrict__ UW,
                          const float* __restrict__ x1, const float* __restrict__ w2,
                          const float* __restrict__ ss2, float* __restrict__ m) {
    const int wid = threadIdx.x >> 6, lane = threadIdx.x & 63;
    const int row = blockIdx.x * 4 + wid;
    const float r = rsqrtf(*ss2 / (float)HD + 1e-6f);
    const float4* Gr = (const float4*)(GW + (size_t)row * HD);
    const float4* Ur = (const float4*)(UW + (size_t)row * HD);
    const float4* xr = (const float4*)x1;
    const float4* wr = (const float4*)w2;
    float ag = 0.f, au = 0.f;
#pragma unroll
    for (int i = 0; i < HD/256; i++) {
        float4 xv = xr[lane + i*64];
        float4 wv = wr[lane + i*64];
        float4 tt = make_float4(xv.x*(1.f+wv.x), xv.y*(1.f+wv.y),
                                xv.z*(1.f+wv.z), xv.w*(1.f+wv.w));
        float4 gv = Gr[lane + i*64];
        float4 uv = Ur[lane + i*64];
        ag += gv.x*tt.x + gv.y*tt.y + gv.z*tt.z + gv.w*tt.w;
        au += uv.x*tt.x + uv.y*tt.y + uv.z*tt.z + uv.w*tt.w;
    }
    ag = waveReduceSum(ag);
    au = waveReduceSum(au);
    if (lane == 0) {
        ag *= r; au *= r;
        m[row] = siluf_(ag) * au;
    }
}

// ---------- K5: down GEMV + residual -> out ----------
__global__ void k5_down(const float* __restrict__ W, const float* __restrict__ m,
                        const float* __restrict__ x1, float* __restrict__ out0) {
    const int wid = threadIdx.x >> 6, lane = threadIdx.x & 63;
    const int row = blockIdx.x * 4 + wid;
    const float4* Wr = (const float4*)(W + (size_t)row * 8192);
    const float4* vr = (const float4*)m;
    float acc = 0.f;
#pragma unroll 8
    for (int i = 0; i < 8192/256; i++) {
        float4 a = Wr[lane + i*64];
        float4 b = vr[lane + i*64];
        acc += a.x*b.x + a.y*b.y + a.z*b.z + a.w*b.w;
    }
    acc = waveReduceSum(acc);
    if (lane == 0) out0[row] = x1[row] + acc;
}

// ---------- launch ----------
extern "C" void kernel_launch(void* const* d_in, const int* in_sizes, int n_in,
                              void* d_out, int out_size, void* d_ws, size_t ws_size,
                              hipStream_t stream) {
    const float* x           = (const float*)d_in[0];
    const float* conv_state  = (const float*)d_in[1];
    const float* ssm_state   = (const float*)d_in[2];
    const float* in_proj_w   = (const float*)d_in[3];
    const float* out_proj_w  = (const float*)d_in[4];
    const float* conv_weight = (const float*)d_in[5];
    const float* A_log       = (const float*)d_in[6];
    const float* dt_bias     = (const float*)d_in[7];
    const float* norm_weight = (const float*)d_in[8];
    const float* rms1_w      = (const float*)d_in[9];
    const float* rms2_w      = (const float*)d_in[10];
    const float* gate_w      = (const float*)d_in[11];
    const float* up_w        = (const float*)d_in[12];
    const float* down_w      = (const float*)d_in[13];

    float* out0          = (float*)d_out;                   // 2048
    float* new_conv      = out0 + HD;                       // 32768
    float* new_ssm       = new_conv + QKVD*4;               // 524288

    // workspace layout (floats)
    float* ws   = (float*)d_ws;
    float* hvec = ws;                 // 2048
    float* proj = hvec + HD;          // 12352
    float* yout = proj + PROJN;       // 4096
    float* x1   = yout + TVD;         // 2048
    float* ss2  = x1 + HD;            // 1 (pad to 4)
    float* mmid = ss2 + 4;            // 8192

    k0_rms1<<<1, 256, 0, stream>>>(x, rms1_w, hvec, ss2);
    gemv_rows<HD><<<PROJN/4, 256, 0, stream>>>(in_proj_w, hvec, proj);
    k2_ssm<<<NVHD, 256, 0, stream>>>(proj, conv_state, conv_weight, ssm_state,
                                     A_log, dt_bias, norm_weight,
                                     new_conv, new_ssm, yout);
    k3_outproj<<<HD/4, 256, 0, stream>>>(out_proj_w, yout, x, x1, ss2);
    k4_gateup<<<8192/4, 256, 0, stream>>>(gate_w, up_w, x1, rms2_w, ss2, mmid);
    k5_down<<<HD/4, 256, 0, stream>>>(down_w, mmid, x1, out0);
}

// Round 3
// 311.267 us; speedup vs baseline: 1.0824x; 1.0824x over previous
//
#include <hip/hip_runtime.h>
#include <math.h>

// Problem dims
#define HD    2048
#define QKVD  8192
#define TVD   4096
#define NVHD  32
#define NKHD  16
#define KDD   128
#define VDD   128
#define PROJN (QKVD + TVD + 2*NVHD)   // 12352

typedef float f4 __attribute__((ext_vector_type(4)));

// ---------- helpers ----------
__device__ __forceinline__ float sigmoidf_(float x) { return 1.0f / (1.0f + expf(-x)); }
__device__ __forceinline__ float siluf_(float x)    { return x / (1.0f + expf(-x)); }
__device__ __forceinline__ float softplusf_(float x){ return (x > 20.0f) ? x : log1pf(expf(x)); }
__device__ __forceinline__ float dot4(f4 a, f4 b)   { return a.x*b.x + a.y*b.y + a.z*b.z + a.w*b.w; }
__device__ __forceinline__ f4 ntload(const f4* p)   { return __builtin_nontemporal_load(p); }

__device__ __forceinline__ float waveReduceSum(float v) {
#pragma unroll
    for (int o = 32; o > 0; o >>= 1) v += __shfl_down(v, o, 64);
    return v;
}

// block reduce over NW waves; `red` needs NW floats of LDS. All threads get result.
template<int NW>
__device__ __forceinline__ float blockReduceSum(float v, float* red) {
    const int lane = threadIdx.x & 63, wid = threadIdx.x >> 6;
    v = waveReduceSum(v);
    if (lane == 0) red[wid] = v;
    __syncthreads();
    float s = 0.f;
#pragma unroll
    for (int w = 0; w < NW; w++) s += red[w];
    __syncthreads();   // safe LDS reuse
    return s;
}

// ---------- K_A: fused rms1 + in_proj GEMV (4 rows/block, 1 wave/row) ----------
__global__ void kA_inproj(const float* __restrict__ x, const float* __restrict__ w1,
                          const float* __restrict__ W, float* __restrict__ proj) {
    __shared__ float red[4];
    __shared__ float hl[HD];
    const int t = threadIdx.x;

    // prologue: rms1 recomputed per block (x, w1 are L2-hot, 16KB)
    f4 xv[2];
    float s = 0.f;
#pragma unroll
    for (int i = 0; i < 2; i++) {
        xv[i] = ((const f4*)x)[t + i*256];
        s += dot4(xv[i], xv[i]);
    }
    s = blockReduceSum<4>(s, red);
    const float r = rsqrtf(s / (float)HD + 1e-6f);
#pragma unroll
    for (int i = 0; i < 2; i++) {
        f4 wv = ((const f4*)w1)[t + i*256];
        ((f4*)hl)[t + i*256] = xv[i] * r * (wv + 1.0f);
    }
    __syncthreads();

    const int wid = t >> 6, lane = t & 63;
    const int row = blockIdx.x * 4 + wid;
    const f4* Wr = (const f4*)(W + (size_t)row * HD);
    float acc = 0.f;
#pragma unroll
    for (int i = 0; i < 8; i++) {
        f4 a = ntload(&Wr[lane + i*64]);
        f4 b = ((const f4*)hl)[lane + i*64];
        acc += dot4(a, b);
    }
    acc = waveReduceSum(acc);
    if (lane == 0) proj[row] = acc;
}

// ---------- K_B: conv update + L2 norms + gated delta-rule + y-gate (512 thr) ----------
__global__ void kB_ssm(const float* __restrict__ proj,
                       const float* __restrict__ conv_state,
                       const float* __restrict__ conv_weight,
                       const float* __restrict__ ssm_state,
                       const float* __restrict__ A_log,
                       const float* __restrict__ dt_bias,
                       const float* __restrict__ norm_weight,
                       float* __restrict__ new_conv_state,
                       float* __restrict__ new_ssm,
                       float* __restrict__ yout) {
    const int head  = blockIdx.x;     // 0..31
    const int t     = threadIdx.x;    // 0..511
    const int qhead = head >> 1;      // ratio = 2

    __shared__ float red[8];
    __shared__ float q_s[KDD], k_s[KDD], v_s[VDD];
    __shared__ float skr2[512], sqr2[512];

    float qv = 0.f, kv = 0.f, vv = 0.f;
    if (t < 128) {
        int cq = qhead*KDD + t;
        f4 cs = *(const f4*)(conv_state + (size_t)cq*4);
        f4 w  = *(const f4*)(conv_weight + (size_t)cq*4);
        float xm = proj[cq];
        qv = siluf_(cs.y*w.x + cs.z*w.y + cs.w*w.z + xm*w.w);
        f4 nc; nc.x = cs.y; nc.y = cs.z; nc.z = cs.w; nc.w = xm;
        *(f4*)(new_conv_state + (size_t)cq*4) = nc;

        int ck = 2048 + qhead*KDD + t;
        cs = *(const f4*)(conv_state + (size_t)ck*4);
        w  = *(const f4*)(conv_weight + (size_t)ck*4);
        xm = proj[ck];
        kv = siluf_(cs.y*w.x + cs.z*w.y + cs.w*w.z + xm*w.w);
        nc.x = cs.y; nc.y = cs.z; nc.z = cs.w; nc.w = xm;
        *(f4*)(new_conv_state + (size_t)ck*4) = nc;

        int cv = 4096 + head*VDD + t;
        cs = *(const f4*)(conv_state + (size_t)cv*4);
        w  = *(const f4*)(conv_weight + (size_t)cv*4);
        xm = proj[cv];
        vv = siluf_(cs.y*w.x + cs.z*w.y + cs.w*w.z + xm*w.w);
        nc.x = cs.y; nc.y = cs.z; nc.z = cs.w; nc.w = xm;
        *(f4*)(new_conv_state + (size_t)cv*4) = nc;
    }

    const float sq = blockReduceSum<8>(qv*qv, red);
    const float sk = blockReduceSum<8>(kv*kv, red);
    const float qn = qv / fmaxf(sqrtf(sq), 1e-12f) * 0.08838834764831845f; // * 128^-0.5
    const float kn = kv / fmaxf(sqrtf(sk), 1e-12f);
    const float kq = blockReduceSum<8>(qn*kn, red);

    if (t < 128) { q_s[t] = qn; k_s[t] = kn; v_s[t] = vv; }
    __syncthreads();

    const float a_raw = proj[QKVD + TVD + head];
    const float b_raw = proj[QKVD + TVD + NVHD + head];
    const float beta  = sigmoidf_(b_raw);
    const float g     = -expf(A_log[head]) * softplusf_(a_raw + dt_bias[head]);
    const float decay = expf(g);

    // pass 1: per-column partial dots over a quarter of the k-range
    const int col = t & 127;
    const int kh  = t >> 7;                // 0..3
    const float* Sp = ssm_state + (size_t)head*KDD*VDD + (size_t)kh*32*VDD + col;
    float skr = 0.f, sqr = 0.f;
#pragma unroll 8
    for (int k = 0; k < 32; k++) {
        float sv = Sp[k*VDD];
        skr += sv * k_s[kh*32 + k];
        sqr += sv * q_s[kh*32 + k];
    }
    skr2[t] = skr; sqr2[t] = sqr;
    __syncthreads();
    const float Skr = skr2[col] + skr2[col+128] + skr2[col+256] + skr2[col+384];
    const float Sqr = sqr2[col] + sqr2[col+128] + sqr2[col+256] + sqr2[col+384];
    const float delta = (v_s[col] - decay * Skr) * beta;

    // pass 2: write new_ssm (re-read is L2-hot)
    float* Np = new_ssm + (size_t)head*KDD*VDD + (size_t)kh*32*VDD + col;
#pragma unroll 8
    for (int k = 0; k < 32; k++) {
        float sv = Sp[k*VDD];
        Np[k*VDD] = decay * sv + k_s[kh*32 + k] * delta;
    }

    // y = decay*<S[:,col],q> + delta*<k,q>
    const float y = decay * Sqr + delta * kq;
    const float sy = blockReduceSum<8>((kh == 0) ? y*y : 0.f, red);
    if (t < 128) {
        const float rr = rsqrtf(sy / (float)VDD + 1e-6f);
        const float z  = proj[QKVD + head*VDD + t];
        yout[head*VDD + t] = y * rr * norm_weight[t] * siluf_(z);
    }
}

// ---------- K_C: out_proj GEMV + residual (1 row/block, 4-wave split-K) ----------
__global__ void kC_outproj(const float* __restrict__ W, const float* __restrict__ y,
                           const float* __restrict__ x, float* __restrict__ x1) {
    __shared__ float part[4];
    const int t = threadIdx.x, wid = t >> 6, lane = t & 63;
    const int row = blockIdx.x;
    const f4* Wr = (const f4*)(W + (size_t)row * TVD);
    const f4* vr = (const f4*)y;
    float acc = 0.f;
#pragma unroll
    for (int i = 0; i < 4; i++) {
        int idx = wid*256 + i*64 + lane;
        acc += dot4(ntload(&Wr[idx]), vr[idx]);
    }
    acc = waveReduceSum(acc);
    if (lane == 0) part[wid] = acc;
    __syncthreads();
    if (t == 0) x1[row] = x[row] + part[0] + part[1] + part[2] + part[3];
}

// ---------- K_D: rms2 prologue + gate/up dual GEMV (4 rows/block) ----------
__global__ void kD_gateup(const float* __restrict__ GW, const float* __restrict__ UW,
                          const float* __restrict__ x1, const float* __restrict__ w2,
                          float* __restrict__ m) {
    __shared__ float red[4];
    __shared__ float tl[HD];
    const int t = threadIdx.x;

    // prologue: rms2 recomputed per block (x1, w2 are L2-hot)
    f4 xv[2];
    float s = 0.f;
#pragma unroll
    for (int i = 0; i < 2; i++) {
        xv[i] = ((const f4*)x1)[t + i*256];
        s += dot4(xv[i], xv[i]);
    }
    s = blockReduceSum<4>(s, red);
    const float r = rsqrtf(s / (float)HD + 1e-6f);
#pragma unroll
    for (int i = 0; i < 2; i++) {
        f4 wv = ((const f4*)w2)[t + i*256];
        ((f4*)tl)[t + i*256] = xv[i] * (wv + 1.0f);   // r folded in at the end
    }
    __syncthreads();

    const int wid = t >> 6, lane = t & 63;
    const int row = blockIdx.x * 4 + wid;
    const f4* Gr = (const f4*)(GW + (size_t)row * HD);
    const f4* Ur = (const f4*)(UW + (size_t)row * HD);
    float ag = 0.f, au = 0.f;
#pragma unroll
    for (int i = 0; i < 8; i++) {
        f4 tt = ((const f4*)tl)[lane + i*64];
        ag += dot4(ntload(&Gr[lane + i*64]), tt);
        au += dot4(ntload(&Ur[lane + i*64]), tt);
    }
    ag = waveReduceSum(ag);
    au = waveReduceSum(au);
    if (lane == 0) {
        ag *= r; au *= r;
        m[row] = siluf_(ag) * au;
    }
}

// ---------- K_E: down GEMV + residual (1 row/block, 4-wave split-K) ----------
__global__ void kE_down(const float* __restrict__ W, const float* __restrict__ m,
                        const float* __restrict__ x1, float* __restrict__ out0) {
    __shared__ float part[4];
    const int t = threadIdx.x, wid = t >> 6, lane = t & 63;
    const int row = blockIdx.x;
    const f4* Wr = (const f4*)(W + (size_t)row * 8192);
    const f4* vr = (const f4*)m;
    float acc = 0.f;
#pragma unroll
    for (int i = 0; i < 8; i++) {
        int idx = wid*512 + i*64 + lane;
        acc += dot4(ntload(&Wr[idx]), vr[idx]);
    }
    acc = waveReduceSum(acc);
    if (lane == 0) part[wid] = acc;
    __syncthreads();
    if (t == 0) out0[row] = x1[row] + part[0] + part[1] + part[2] + part[3];
}

// ---------- launch ----------
extern "C" void kernel_launch(void* const* d_in, const int* in_sizes, int n_in,
                              void* d_out, int out_size, void* d_ws, size_t ws_size,
                              hipStream_t stream) {
    const float* x           = (const float*)d_in[0];
    const float* conv_state  = (const float*)d_in[1];
    const float* ssm_state   = (const float*)d_in[2];
    const float* in_proj_w   = (const float*)d_in[3];
    const float* out_proj_w  = (const float*)d_in[4];
    const float* conv_weight = (const float*)d_in[5];
    const float* A_log       = (const float*)d_in[6];
    const float* dt_bias     = (const float*)d_in[7];
    const float* norm_weight = (const float*)d_in[8];
    const float* rms1_w      = (const float*)d_in[9];
    const float* rms2_w      = (const float*)d_in[10];
    const float* gate_w      = (const float*)d_in[11];
    const float* up_w        = (const float*)d_in[12];
    const float* down_w      = (const float*)d_in[13];

    float* out0     = (float*)d_out;        // 2048
    float* new_conv = out0 + HD;            // 32768
    float* new_ssm  = new_conv + QKVD*4;    // 524288

    float* ws   = (float*)d_ws;
    float* proj = ws;                 // 12352
    float* yout = proj + PROJN;       // 4096
    float* x1   = yout + TVD;         // 2048
    float* mmid = x1 + HD;            // 8192

    kA_inproj<<<PROJN/4, 256, 0, stream>>>(x, rms1_w, in_proj_w, proj);
    kB_ssm<<<NVHD, 512, 0, stream>>>(proj, conv_state, conv_weight, ssm_state,
                                     A_log, dt_bias, norm_weight,
                                     new_conv, new_ssm, yout);
    kC_outproj<<<HD, 256, 0, stream>>>(out_proj_w, yout, x, x1);
    kD_gateup<<<8192/4, 256, 0, stream>>>(gate_w, up_w, x1, rms2_w, mmid);
    kE_down<<<HD, 256, 0, stream>>>(down_w, mmid, x1, out0);
}